// Round 12
// baseline (549.849 us; speedup 1.0000x reference)
//
#include <hip/hip_runtime.h>

#define DK 256    // K dim of every GEMM (D_IN == D_HID == 256)
#define BN 256    // nodes per CSR bucket (dst >> 8)
#define NBLK 512  // partition blocks for hist/part

typedef __attribute__((ext_vector_type(8))) short bf16x8;   // 8 bf16 in 4 VGPRs
typedef __attribute__((ext_vector_type(4))) float f32x4;

__device__ __forceinline__ unsigned short f2b(float f) {    // RNE fp32->bf16
    unsigned u = __builtin_bit_cast(unsigned, f);
    u += 0x7FFFu + ((u >> 16) & 1u);
    return (unsigned short)(u >> 16);
}
__device__ __forceinline__ float b2f(unsigned short s) {
    return __builtin_bit_cast(float, (unsigned)s << 16);
}
__device__ __forceinline__ void gld_lds16(void* lds, const void* g) {
    __builtin_amdgcn_global_load_lds(
        (const __attribute__((address_space(1))) unsigned int*)g,
        (__attribute__((address_space(3))) unsigned int*)lds, 16, 0, 0);
}

// ---------------------------------------------------------------------------
// fp32 -> bf16 conversion, 4 elems/thread (x)
// ---------------------------------------------------------------------------
__global__ __launch_bounds__(256) void k_cvt(const float* __restrict__ src,
                                             unsigned short* __restrict__ dst, int n4) {
    int i = blockIdx.x * 256 + threadIdx.x;
    if (i < n4) {
        float4 v = reinterpret_cast<const float4*>(src)[i];
        ushort4 o = make_ushort4(f2b(v.x), f2b(v.y), f2b(v.z), f2b(v.w));
        reinterpret_cast<ushort4*>(dst)[i] = o;
    }
}

// all four weight matrices in one launch (regions of float4 units)
__global__ __launch_bounds__(256) void k_cvtw(const float* __restrict__ a,
                                              const float* __restrict__ b,
                                              const float* __restrict__ c,
                                              const float* __restrict__ d,
                                              unsigned short* __restrict__ Wb1,
                                              unsigned short* __restrict__ Wb2) {
    int i = blockIdx.x * 256 + threadIdx.x;   // 49152 total float4 groups
    const float* s;
    unsigned short* o;
    if (i < 16384)      { s = a; o = Wb1; }
    else if (i < 32768) { s = b; o = Wb1 + 256 * 256; i -= 16384; }
    else if (i < 40960) { s = c; o = Wb2;             i -= 32768; }
    else                { s = d; o = Wb2 + 128 * 256; i -= 40960; }
    float4 v = reinterpret_cast<const float4*>(s)[i];
    ushort4 w = make_ushort4(f2b(v.x), f2b(v.y), f2b(v.z), f2b(v.w));
    reinterpret_cast<ushort4*>(o)[i] = w;
}

// ---------------------------------------------------------------------------
// 3-kernel exclusive scan for the histogram (1024 elems/block)
// ---------------------------------------------------------------------------
__global__ __launch_bounds__(256) void k_scan_a(const int* __restrict__ in,
                                                int* __restrict__ bsum, int N) {
    __shared__ int sm[256];
    int t = threadIdx.x;
    int i0 = blockIdx.x * 1024 + t * 4;
    int s = 0;
    if (i0 + 3 < N) {
        int4 v = *reinterpret_cast<const int4*>(in + i0);
        s = v.x + v.y + v.z + v.w;
    } else {
        for (int i = i0; i < min(i0 + 4, N); ++i) s += in[i];
    }
    sm[t] = s;
    __syncthreads();
    for (int off = 128; off > 0; off >>= 1) {
        if (t < off) sm[t] += sm[t + off];
        __syncthreads();
    }
    if (t == 0) bsum[blockIdx.x] = sm[0];
}

__global__ __launch_bounds__(256) void k_scan_b(const int* __restrict__ bsum,
                                                int* __restrict__ boff,
                                                int* __restrict__ totN, int NB) {
    __shared__ int sm[256];
    int t = threadIdx.x;
    sm[t] = (t < NB) ? bsum[t] : 0;
    __syncthreads();
    for (int off = 1; off < 256; off <<= 1) {
        int v = (t >= off) ? sm[t - off] : 0;
        __syncthreads();
        sm[t] += v;
        __syncthreads();
    }
    if (t < NB) boff[t] = (t == 0) ? 0 : sm[t - 1];
    if (t == NB - 1) *totN = sm[t];
}

__global__ __launch_bounds__(256) void k_scan_c2(const int* __restrict__ in,
                                                 const int* __restrict__ boff,
                                                 int* __restrict__ outx, int N) {
    __shared__ int sm[256];
    int t = threadIdx.x;
    int i0 = blockIdx.x * 1024 + t * 4;
    int d0 = 0, d1 = 0, d2 = 0, d3 = 0;
    if (i0 + 3 < N) {
        int4 v = *reinterpret_cast<const int4*>(in + i0);
        d0 = v.x; d1 = v.y; d2 = v.z; d3 = v.w;
    } else {
        if (i0 + 0 < N) d0 = in[i0 + 0];
        if (i0 + 1 < N) d1 = in[i0 + 1];
        if (i0 + 2 < N) d2 = in[i0 + 2];
        if (i0 + 3 < N) d3 = in[i0 + 3];
    }
    int s = d0 + d1 + d2 + d3;
    sm[t] = s;
    __syncthreads();
    for (int off = 1; off < 256; off <<= 1) {
        int v = (t >= off) ? sm[t - off] : 0;
        __syncthreads();
        sm[t] += v;
        __syncthreads();
    }
    int run = boff[blockIdx.x] + sm[t] - s;
    int dd[4] = {d0, d1, d2, d3};
#pragma unroll
    for (int i = 0; i < 4; ++i) {
        int idx = i0 + i;
        if (idx < N) { outx[idx] = run; run += dd[i]; }
    }
}

// ---------------------------------------------------------------------------
// CSR build via deterministic counting-sort partition (no global atomics)
// ---------------------------------------------------------------------------
__global__ __launch_bounds__(256) void k_hist(const int* __restrict__ dst,
                                              int* __restrict__ hist,
                                              int E, int NBUK) {
    extern __shared__ int h[];
    int t = threadIdx.x;
    for (int b = t; b < NBUK; b += 256) h[b] = 0;
    __syncthreads();
    int CH = (E + NBLK - 1) / NBLK;
    int beg = blockIdx.x * CH;
    int end = min(beg + CH, E);
    for (int i = beg + t; i < end; i += 256)
        atomicAdd(&h[dst[i] >> 8], 1);
    __syncthreads();
    for (int b = t; b < NBUK; b += 256)
        hist[b * NBLK + blockIdx.x] = h[b];     // bucket-major for the scan
}

__global__ __launch_bounds__(256) void k_part(const int* __restrict__ src,
                                              const int* __restrict__ dst,
                                              const int* __restrict__ hoff,
                                              unsigned* __restrict__ scratch,
                                              int E, int NBUK) {
    extern __shared__ int cur[];
    int t = threadIdx.x;
    for (int b = t; b < NBUK; b += 256) cur[b] = hoff[b * NBLK + blockIdx.x];
    __syncthreads();
    int CH = (E + NBLK - 1) / NBLK;
    int beg = blockIdx.x * CH;
    int end = min(beg + CH, E);
    for (int i = beg + t; i < end; i += 256) {
        int d = dst[i];
        int p = atomicAdd(&cur[d >> 8], 1);     // LDS atomic only
        scratch[p] = (unsigned)src[i] | ((unsigned)(d & 255) << 20);
    }
}

// FUSED: per-bucket degree count + block prefix scan -> rowptr/invdeg,
// then CSR scatter — replaces k_degb + 3 scan kernels + k_scatter2.
// Bucket range is ~16KB so the second scratch pass hits L2.
__global__ __launch_bounds__(256) void k_scatter3(const unsigned* __restrict__ scratch,
                                                  const int* __restrict__ hoff,
                                                  int* __restrict__ rowptr,
                                                  float* __restrict__ invdeg,
                                                  int* __restrict__ col,
                                                  int E, int NBUK, int N) {
    __shared__ int cnt[BN];
    __shared__ int sm[256];
    __shared__ int cur[BN];
    int b = blockIdx.x, t = threadIdx.x;
    cnt[t] = 0;
    __syncthreads();
    int beg = hoff[b * NBLK];
    int end = (b + 1 < NBUK) ? hoff[(b + 1) * NBLK] : E;
    for (int i = beg + t; i < end; i += 256)
        atomicAdd(&cnt[scratch[i] >> 20], 1);
    __syncthreads();
    int v = cnt[t];
    sm[t] = v;
    __syncthreads();
    for (int off = 1; off < 256; off <<= 1) {   // inclusive scan
        int u = (t >= off) ? sm[t - off] : 0;
        __syncthreads();
        sm[t] += u;
        __syncthreads();
    }
    int node = b * BN + t;
    if (node < N) {
        int start = beg + sm[t] - v;            // exclusive prefix
        rowptr[node] = start;
        cur[t] = start;
        invdeg[node] = 1.0f / fmaxf((float)v, 1.0f);
    }
    if (b == 0 && t == 0) rowptr[N] = E;
    __syncthreads();
    for (int i = beg + t; i < end; i += 256) {
        unsigned s = scratch[i];
        int p = atomicAdd(&cur[s >> 20], 1);    // LDS atomic only
        col[p] = (int)(s & 0xFFFFFu);
    }
}

// ---------------------------------------------------------------------------
// bf16 MFMA GEMM: C[m,n] = A[m,:]·W[n,:], K=256, NT column tiles of 128.
// All NT tiles of one 128-row stripe run in ONE block (sequential nt loop):
// A tile re-reads hit the same-XCD L2 instead of HBM.
// Output split: cols [0,NT*64) -> Y (bf16); cols [NT*64,NT*128) -> R.
// ---------------------------------------------------------------------------
template <bool RF32, int NT>
__global__ __launch_bounds__(256) void k_gemm_bf16(const unsigned short* __restrict__ A,
                                                   const unsigned short* __restrict__ W,
                                                   unsigned short* __restrict__ Y,
                                                   void* __restrict__ Rv, int N) {
    constexpr int DOUTA = NT * 64;
    __shared__ unsigned short As[128 * 32];   // [row][k] bf16, unpadded (global_load_lds)
    __shared__ unsigned short Bs[128 * 32];
    const int tid  = threadIdx.x;
    const int lane = tid & 63;
    const int w    = tid >> 6;
    const int wm   = w & 1, wn = w >> 1;
    const int m0   = blockIdx.x * 128;
    const int lm   = lane & 15, quad = lane >> 4;

    // staging geometry: 8 chunks of 16 rows per tile; wave w stages chunks 2w,2w+1
    const int srow  = lane >> 2;        // row within chunk
    const int skoff = (lane & 3) * 8;   // bf16 offset within 32-wide k slice
    const int ca = 2 * w, cb = 2 * w + 1;

    for (int nt = 0; nt < NT; ++nt) {
        const int n0 = nt * 128;
        f32x4 acc[4][4];
#pragma unroll
        for (int i = 0; i < 4; ++i)
#pragma unroll
            for (int j = 0; j < 4; ++j) acc[i][j] = (f32x4){0.f, 0.f, 0.f, 0.f};

        for (int k0 = 0; k0 < DK; k0 += 32) {
            int ra = min(m0 + 16 * ca + srow, N - 1);   // clamp M tail (stores masked)
            int rb = min(m0 + 16 * cb + srow, N - 1);
            gld_lds16(As + ca * 512, A + (size_t)ra * DK + k0 + skoff);
            gld_lds16(As + cb * 512, A + (size_t)rb * DK + k0 + skoff);
            int na = n0 + 16 * ca + srow;               // W rows = NT*128 -> in bounds
            int nb = n0 + 16 * cb + srow;
            gld_lds16(Bs + ca * 512, W + (size_t)na * DK + k0 + skoff);
            gld_lds16(Bs + cb * 512, W + (size_t)nb * DK + k0 + skoff);
            __syncthreads();

            bf16x8 af[4], bfr[4];
#pragma unroll
            for (int mt = 0; mt < 4; ++mt)
                af[mt] = *reinterpret_cast<const bf16x8*>(As + (wm * 64 + mt * 16 + lm) * 32 + quad * 8);
#pragma unroll
            for (int ntf = 0; ntf < 4; ++ntf)
                bfr[ntf] = *reinterpret_cast<const bf16x8*>(Bs + (wn * 64 + ntf * 16 + lm) * 32 + quad * 8);
#pragma unroll
            for (int mt = 0; mt < 4; ++mt)
#pragma unroll
                for (int ntf = 0; ntf < 4; ++ntf)
                    acc[mt][ntf] = __builtin_amdgcn_mfma_f32_16x16x32_bf16(af[mt], bfr[ntf], acc[mt][ntf], 0, 0, 0);
            __syncthreads();
        }

        const bool yPart = (n0 < DOUTA);
#pragma unroll
        for (int mt = 0; mt < 4; ++mt) {
#pragma unroll
            for (int ntf = 0; ntf < 4; ++ntf) {
                int gn = n0 + wn * 64 + ntf * 16 + lm;
#pragma unroll
                for (int reg = 0; reg < 4; ++reg) {
                    int gm = m0 + wm * 64 + mt * 16 + quad * 4 + reg;
                    if (gm < N) {
                        float v = acc[mt][ntf][reg];
                        if (yPart) {
                            Y[(size_t)gm * DOUTA + gn] = f2b(v);
                        } else if (RF32) {
                            ((float*)Rv)[(size_t)gm * DOUTA + (gn - DOUTA)] = v;
                        } else {
                            ((unsigned short*)Rv)[(size_t)gm * DOUTA + (gn - DOUTA)] = f2b(v);
                        }
                    }
                }
            }
        }
    }
}

// ---------------------------------------------------------------------------
// layer-1 aggregate, HALF-FEATURE pass P: H[:,P*128:(P+1)*128] =
// relu(mean(Y[nbrs])+bias+R) on feature half P. Two grid-wide launches so the
// gather working set per pass is 25.6 MB (tests/exploits L3 retention).
// Wave halves process two edges: 32 lanes x 8B per 256B half-row.
// Edge iteration order identical to the full-width version -> bitwise-same H.
// ---------------------------------------------------------------------------
template <int P>
__global__ __launch_bounds__(256) void k_agg256h(const unsigned short* __restrict__ Y,
                                                 const unsigned short* __restrict__ Rb,
                                                 const float* __restrict__ bias,
                                                 const float* __restrict__ invdeg,
                                                 const int* __restrict__ rowptr,
                                                 const int* __restrict__ col,
                                                 unsigned short* __restrict__ H, int N) {
    int g = blockIdx.x * 256 + threadIdx.x;
    int node = g >> 6;
    int lane = g & 63;
    if (node >= N) return;
    int half = lane >> 5, sub = lane & 31;
    int beg = rowptr[node], end = rowptr[node + 1];
    const unsigned short* yb = Y + P * 128 + sub * 4;
    float a0 = 0, a1 = 0, a2 = 0, a3 = 0;
    int e = beg;
    for (; e + 7 < end; e += 8) {                 // 4 pairs = 8 edges in flight
        int s[4];
#pragma unroll
        for (int u = 0; u < 4; ++u) s[u] = col[e + 2 * u + half];
        ushort4 v[4];
#pragma unroll
        for (int u = 0; u < 4; ++u)
            v[u] = *reinterpret_cast<const ushort4*>(yb + (size_t)s[u] * 256);
#pragma unroll
        for (int u = 0; u < 4; ++u) {
            a0 += b2f(v[u].x); a1 += b2f(v[u].y);
            a2 += b2f(v[u].z); a3 += b2f(v[u].w);
        }
    }
    for (; e + 1 < end; e += 2) {                 // leftover pairs
        int s0 = col[e + half];
        ushort4 v0 = *reinterpret_cast<const ushort4*>(yb + (size_t)s0 * 256);
        a0 += b2f(v0.x); a1 += b2f(v0.y); a2 += b2f(v0.z); a3 += b2f(v0.w);
    }
    if (e < end && half == 0) {                   // odd final edge: half 0 only
        int s0 = col[e];
        ushort4 v0 = *reinterpret_cast<const ushort4*>(yb + (size_t)s0 * 256);
        a0 += b2f(v0.x); a1 += b2f(v0.y); a2 += b2f(v0.z); a3 += b2f(v0.w);
    }
    a0 += __shfl_xor(a0, 32);
    a1 += __shfl_xor(a1, 32);
    a2 += __shfl_xor(a2, 32);
    a3 += __shfl_xor(a3, 32);
    if (half == 0) {
        float inv = invdeg[node];
        int c = P * 128 + sub * 4;
        ushort4 r = *reinterpret_cast<const ushort4*>(Rb + (size_t)node * 256 + c);
        f32x4 bv = *reinterpret_cast<const f32x4*>(bias + c);
        float o0 = fmaxf(a0 * inv + bv[0] + b2f(r.x), 0.f);
        float o1 = fmaxf(a1 * inv + bv[1] + b2f(r.y), 0.f);
        float o2 = fmaxf(a2 * inv + bv[2] + b2f(r.z), 0.f);
        float o3 = fmaxf(a3 * inv + bv[3] + b2f(r.w), 0.f);
        *reinterpret_cast<ushort4*>(H + (size_t)node * 256 + c) =
            make_ushort4(f2b(o0), f2b(o1), f2b(o2), f2b(o3));
    }
}

// ---------------------------------------------------------------------------
// layer-2 aggregate: O = mean(Y[nbrs]) + bias + R, width 128, fp32 out.
// Wave halves process two edges: 32 lanes x 8B per 256B row. (Unsplit: control.)
// ---------------------------------------------------------------------------
__global__ __launch_bounds__(256) void k_agg128(const unsigned short* __restrict__ Y,
                                                const float* __restrict__ Rf,
                                                const float* __restrict__ bias,
                                                const float* __restrict__ invdeg,
                                                const int* __restrict__ rowptr,
                                                const int* __restrict__ col,
                                                float* __restrict__ O, int N) {
    int g = blockIdx.x * 256 + threadIdx.x;
    int node = g >> 6;
    int lane = g & 63;
    if (node >= N) return;
    int half = lane >> 5, sub = lane & 31;
    int beg = rowptr[node], end = rowptr[node + 1];
    const unsigned short* yb = Y + sub * 4;
    float a0 = 0, a1 = 0, a2 = 0, a3 = 0;
    int e = beg;
    for (; e + 7 < end; e += 8) {                 // 4 pairs = 8 edges in flight
        int s[4];
#pragma unroll
        for (int u = 0; u < 4; ++u) s[u] = col[e + 2 * u + half];
        ushort4 v[4];
#pragma unroll
        for (int u = 0; u < 4; ++u)
            v[u] = *reinterpret_cast<const ushort4*>(yb + (size_t)s[u] * 128);
#pragma unroll
        for (int u = 0; u < 4; ++u) {
            a0 += b2f(v[u].x); a1 += b2f(v[u].y);
            a2 += b2f(v[u].z); a3 += b2f(v[u].w);
        }
    }
    for (; e + 1 < end; e += 2) {
        int s0 = col[e + half];
        ushort4 v0 = *reinterpret_cast<const ushort4*>(yb + (size_t)s0 * 128);
        a0 += b2f(v0.x); a1 += b2f(v0.y); a2 += b2f(v0.z); a3 += b2f(v0.w);
    }
    if (e < end && half == 0) {
        int s0 = col[e];
        ushort4 v0 = *reinterpret_cast<const ushort4*>(yb + (size_t)s0 * 128);
        a0 += b2f(v0.x); a1 += b2f(v0.y); a2 += b2f(v0.z); a3 += b2f(v0.w);
    }
    a0 += __shfl_xor(a0, 32);
    a1 += __shfl_xor(a1, 32);
    a2 += __shfl_xor(a2, 32);
    a3 += __shfl_xor(a3, 32);
    if (half == 0) {
        float inv = invdeg[node];
        int c = sub * 4;
        f32x4 r = *reinterpret_cast<const f32x4*>(Rf + (size_t)node * 128 + c);
        f32x4 bv = *reinterpret_cast<const f32x4*>(bias + c);
        f32x4 o;
        o[0] = a0 * inv + bv[0] + r[0];
        o[1] = a1 * inv + bv[1] + r[1];
        o[2] = a2 * inv + bv[2] + r[2];
        o[3] = a3 * inv + bv[3] + r[3];
        *reinterpret_cast<f32x4*>(O + (size_t)node * 128 + c) = o;
    }
}

// ---------------------------------------------------------------------------
extern "C" void kernel_launch(void* const* d_in, const int* in_sizes, int n_in,
                              void* d_out, int out_size, void* d_ws, size_t ws_size,
                              hipStream_t stream) {
    const float* x   = (const float*)d_in[0];
    const int*   ei  = (const int*)d_in[1];
    const float* W1l = (const float*)d_in[2];
    const float* b1  = (const float*)d_in[3];
    const float* W1r = (const float*)d_in[4];
    const float* W2l = (const float*)d_in[5];
    const float* b2  = (const float*)d_in[6];
    const float* W2r = (const float*)d_in[7];
    float* out = (float*)d_out;

    const int N = in_sizes[0] / DK;   // 100000
    const int E = in_sizes[1] / 2;    // 1600000
    const int* src = ei;
    const int* dst = ei + E;

    // workspace regions (each N*256 shorts = 51.2 MB):
    //   xb | y1b (y2b aliases after agg256) | r1b (r2f aliases) | hb
    //   Wb1 Wb2 | invdeg | rowptr | col | bsum | boff
    // CSR temporaries alias dead GEMM buffers:
    //   scratch u32[E] -> hb ; hist/hoff -> y1b
    unsigned short* xb  = (unsigned short*)d_ws;
    unsigned short* y1b = xb + (size_t)N * 256;
    unsigned short* r1b = y1b + (size_t)N * 256;
    unsigned short* hb  = r1b + (size_t)N * 256;
    unsigned short* Wb1 = hb + (size_t)N * 256;
    unsigned short* Wb2 = Wb1 + 512 * 256;
    float* invdeg = (float*)(Wb2 + 256 * 256);
    int* rowptr = (int*)(invdeg + N);
    int* col    = rowptr + (N + 1);
    int* bsum   = col + E;
    int* boff   = bsum + 512;
    unsigned short* y2b = y1b;          // y1b dead after k_agg256h passes
    float* r2f = (float*)r1b;           // r1b dead after k_agg256h passes

    const int NBUK = (N + BN - 1) / BN;       // 391 buckets
    const int NH   = NBUK * NBLK;             // 200192 histogram entries
    unsigned* scratch = (unsigned*)hb;        // dead before agg writes hb
    int* hist  = (int*)y1b;                   // dead before layer-1 GEMM
    int* hoff  = hist + NH;
    int* tot2  = boff + 512;                  // dummy total sink

    // ---- conversions to bf16 ----
    k_cvt<<<(N * 64 + 255) / 256, 256, 0, stream>>>(x, xb, N * 64);
    k_cvtw<<<192, 256, 0, stream>>>(W1l, W1r, W2l, W2r, Wb1, Wb2);

    // ---- CSR build (counting sort; rowptr/invdeg fused into scatter) ----
    const int NB2 = (NH + 1023) / 1024;       // 196 scan blocks for histogram
    k_hist<<<NBLK, 256, NBUK * sizeof(int), stream>>>(dst, hist, E, NBUK);
    k_scan_a<<<NB2, 256, 0, stream>>>(hist, bsum, NH);
    k_scan_b<<<1, 256, 0, stream>>>(bsum, boff, tot2, NB2);
    k_scan_c2<<<NB2, 256, 0, stream>>>(hist, boff, hoff, NH);
    k_part<<<NBLK, 256, NBUK * sizeof(int), stream>>>(src, dst, hoff, scratch, E, NBUK);
    k_scatter3<<<NBUK, 256, 0, stream>>>(scratch, hoff, rowptr, invdeg, col, E, NBUK, N);

    int mTiles = (N + 127) / 128;       // 782
    int aggBlocks = (N + 3) / 4;        // 4 nodes (waves) per block

    // ---- layer 1 ----
    k_gemm_bf16<false, 4><<<mTiles, 256, 0, stream>>>(xb, Wb1, y1b, r1b, N);
    k_agg256h<0><<<aggBlocks, 256, 0, stream>>>(y1b, r1b, b1, invdeg, rowptr, col, hb, N);
    k_agg256h<1><<<aggBlocks, 256, 0, stream>>>(y1b, r1b, b1, invdeg, rowptr, col, hb, N);

    // ---- layer 2 ----
    k_gemm_bf16<true, 2><<<mTiles, 256, 0, stream>>>(hb, Wb2, y2b, r2f, N);
    k_agg128<<<aggBlocks, 256, 0, stream>>>(y2b, r2f, b2, invdeg, rowptr, col, out, N);
}

// Round 13
// 525.751 us; speedup vs baseline: 1.0458x; 1.0458x over previous
//
#include <hip/hip_runtime.h>

#define DK 256    // K dim of every GEMM (D_IN == D_HID == 256)
#define BN 256    // nodes per CSR bucket (dst >> 8)
#define NBLK 512  // partition blocks for hist/part

typedef __attribute__((ext_vector_type(8))) short bf16x8;   // 8 bf16 in 4 VGPRs
typedef __attribute__((ext_vector_type(4))) float f32x4;

__device__ __forceinline__ unsigned short f2b(float f) {    // RNE fp32->bf16
    unsigned u = __builtin_bit_cast(unsigned, f);
    u += 0x7FFFu + ((u >> 16) & 1u);
    return (unsigned short)(u >> 16);
}
__device__ __forceinline__ float b2f(unsigned short s) {
    return __builtin_bit_cast(float, (unsigned)s << 16);
}
__device__ __forceinline__ void gld_lds16(void* lds, const void* g) {
    __builtin_amdgcn_global_load_lds(
        (const __attribute__((address_space(1))) unsigned int*)g,
        (__attribute__((address_space(3))) unsigned int*)lds, 16, 0, 0);
}

// ---------------------------------------------------------------------------
// fp32 -> bf16 conversion, 4 elems/thread (x)
// ---------------------------------------------------------------------------
__global__ __launch_bounds__(256) void k_cvt(const float* __restrict__ src,
                                             unsigned short* __restrict__ dst, int n4) {
    int i = blockIdx.x * 256 + threadIdx.x;
    if (i < n4) {
        float4 v = reinterpret_cast<const float4*>(src)[i];
        ushort4 o = make_ushort4(f2b(v.x), f2b(v.y), f2b(v.z), f2b(v.w));
        reinterpret_cast<ushort4*>(dst)[i] = o;
    }
}

// all four weight matrices in one launch (regions of float4 units)
__global__ __launch_bounds__(256) void k_cvtw(const float* __restrict__ a,
                                              const float* __restrict__ b,
                                              const float* __restrict__ c,
                                              const float* __restrict__ d,
                                              unsigned short* __restrict__ Wb1,
                                              unsigned short* __restrict__ Wb2) {
    int i = blockIdx.x * 256 + threadIdx.x;   // 49152 total float4 groups
    const float* s;
    unsigned short* o;
    if (i < 16384)      { s = a; o = Wb1; }
    else if (i < 32768) { s = b; o = Wb1 + 256 * 256; i -= 16384; }
    else if (i < 40960) { s = c; o = Wb2;             i -= 32768; }
    else                { s = d; o = Wb2 + 128 * 256; i -= 40960; }
    float4 v = reinterpret_cast<const float4*>(s)[i];
    ushort4 w = make_ushort4(f2b(v.x), f2b(v.y), f2b(v.z), f2b(v.w));
    reinterpret_cast<ushort4*>(o)[i] = w;
}

// ---------------------------------------------------------------------------
// 3-kernel exclusive scan for the histogram (1024 elems/block)
// ---------------------------------------------------------------------------
__global__ __launch_bounds__(256) void k_scan_a(const int* __restrict__ in,
                                                int* __restrict__ bsum, int N) {
    __shared__ int sm[256];
    int t = threadIdx.x;
    int i0 = blockIdx.x * 1024 + t * 4;
    int s = 0;
    if (i0 + 3 < N) {
        int4 v = *reinterpret_cast<const int4*>(in + i0);
        s = v.x + v.y + v.z + v.w;
    } else {
        for (int i = i0; i < min(i0 + 4, N); ++i) s += in[i];
    }
    sm[t] = s;
    __syncthreads();
    for (int off = 128; off > 0; off >>= 1) {
        if (t < off) sm[t] += sm[t + off];
        __syncthreads();
    }
    if (t == 0) bsum[blockIdx.x] = sm[0];
}

__global__ __launch_bounds__(256) void k_scan_b(const int* __restrict__ bsum,
                                                int* __restrict__ boff,
                                                int* __restrict__ totN, int NB) {
    __shared__ int sm[256];
    int t = threadIdx.x;
    sm[t] = (t < NB) ? bsum[t] : 0;
    __syncthreads();
    for (int off = 1; off < 256; off <<= 1) {
        int v = (t >= off) ? sm[t - off] : 0;
        __syncthreads();
        sm[t] += v;
        __syncthreads();
    }
    if (t < NB) boff[t] = (t == 0) ? 0 : sm[t - 1];
    if (t == NB - 1) *totN = sm[t];
}

__global__ __launch_bounds__(256) void k_scan_c2(const int* __restrict__ in,
                                                 const int* __restrict__ boff,
                                                 int* __restrict__ outx, int N) {
    __shared__ int sm[256];
    int t = threadIdx.x;
    int i0 = blockIdx.x * 1024 + t * 4;
    int d0 = 0, d1 = 0, d2 = 0, d3 = 0;
    if (i0 + 3 < N) {
        int4 v = *reinterpret_cast<const int4*>(in + i0);
        d0 = v.x; d1 = v.y; d2 = v.z; d3 = v.w;
    } else {
        if (i0 + 0 < N) d0 = in[i0 + 0];
        if (i0 + 1 < N) d1 = in[i0 + 1];
        if (i0 + 2 < N) d2 = in[i0 + 2];
        if (i0 + 3 < N) d3 = in[i0 + 3];
    }
    int s = d0 + d1 + d2 + d3;
    sm[t] = s;
    __syncthreads();
    for (int off = 1; off < 256; off <<= 1) {
        int v = (t >= off) ? sm[t - off] : 0;
        __syncthreads();
        sm[t] += v;
        __syncthreads();
    }
    int run = boff[blockIdx.x] + sm[t] - s;
    int dd[4] = {d0, d1, d2, d3};
#pragma unroll
    for (int i = 0; i < 4; ++i) {
        int idx = i0 + i;
        if (idx < N) { outx[idx] = run; run += dd[i]; }
    }
}

// ---------------------------------------------------------------------------
// CSR build via deterministic counting-sort partition (no global atomics)
// ---------------------------------------------------------------------------
__global__ __launch_bounds__(256) void k_hist(const int* __restrict__ dst,
                                              int* __restrict__ hist,
                                              int E, int NBUK) {
    extern __shared__ int h[];
    int t = threadIdx.x;
    for (int b = t; b < NBUK; b += 256) h[b] = 0;
    __syncthreads();
    int CH = (E + NBLK - 1) / NBLK;
    int beg = blockIdx.x * CH;
    int end = min(beg + CH, E);
    for (int i = beg + t; i < end; i += 256)
        atomicAdd(&h[dst[i] >> 8], 1);
    __syncthreads();
    for (int b = t; b < NBUK; b += 256)
        hist[b * NBLK + blockIdx.x] = h[b];     // bucket-major for the scan
}

__global__ __launch_bounds__(256) void k_part(const int* __restrict__ src,
                                              const int* __restrict__ dst,
                                              const int* __restrict__ hoff,
                                              unsigned* __restrict__ scratch,
                                              int E, int NBUK) {
    extern __shared__ int cur[];
    int t = threadIdx.x;
    for (int b = t; b < NBUK; b += 256) cur[b] = hoff[b * NBLK + blockIdx.x];
    __syncthreads();
    int CH = (E + NBLK - 1) / NBLK;
    int beg = blockIdx.x * CH;
    int end = min(beg + CH, E);
    for (int i = beg + t; i < end; i += 256) {
        int d = dst[i];
        int p = atomicAdd(&cur[d >> 8], 1);     // LDS atomic only
        scratch[p] = (unsigned)src[i] | ((unsigned)(d & 255) << 20);
    }
}

// FUSED: per-bucket degree count + block prefix scan -> rowptr/invdeg,
// then CSR scatter. Bucket range ~16KB so the second scratch pass hits L2.
__global__ __launch_bounds__(256) void k_scatter3(const unsigned* __restrict__ scratch,
                                                  const int* __restrict__ hoff,
                                                  int* __restrict__ rowptr,
                                                  float* __restrict__ invdeg,
                                                  int* __restrict__ col,
                                                  int E, int NBUK, int N) {
    __shared__ int cnt[BN];
    __shared__ int sm[256];
    __shared__ int cur[BN];
    int b = blockIdx.x, t = threadIdx.x;
    cnt[t] = 0;
    __syncthreads();
    int beg = hoff[b * NBLK];
    int end = (b + 1 < NBUK) ? hoff[(b + 1) * NBLK] : E;
    for (int i = beg + t; i < end; i += 256)
        atomicAdd(&cnt[scratch[i] >> 20], 1);
    __syncthreads();
    int v = cnt[t];
    sm[t] = v;
    __syncthreads();
    for (int off = 1; off < 256; off <<= 1) {   // inclusive scan
        int u = (t >= off) ? sm[t - off] : 0;
        __syncthreads();
        sm[t] += u;
        __syncthreads();
    }
    int node = b * BN + t;
    if (node < N) {
        int start = beg + sm[t] - v;            // exclusive prefix
        rowptr[node] = start;
        cur[t] = start;
        invdeg[node] = 1.0f / fmaxf((float)v, 1.0f);
    }
    if (b == 0 && t == 0) rowptr[N] = E;
    __syncthreads();
    for (int i = beg + t; i < end; i += 256) {
        unsigned s = scratch[i];
        int p = atomicAdd(&cur[s >> 20], 1);    // LDS atomic only
        col[p] = (int)(s & 0xFFFFFu);
    }
}

// ---------------------------------------------------------------------------
// bf16 MFMA GEMM: C[m,n] = A[m,:]·W[n,:], K=256, NT column tiles of 128.
// BK=64 (half the barriers of BK=32; 32 MFMA per stage). LDS rows are 128B:
// unswizzled that is a 16-way bank conflict on ds_read_b128, so the 16B
// chunk index is XOR-swizzled with row&7 (rule #21: linear global_load_lds
// dest + inverse-permuted GLOBAL source k-offset + same XOR on the read).
// Output split: cols [0,NT*64) -> Y (bf16); cols [NT*64,NT*128) -> R.
// ---------------------------------------------------------------------------
template <bool RF32, int NT>
__global__ __launch_bounds__(256) void k_gemm_bf16(const unsigned short* __restrict__ A,
                                                   const unsigned short* __restrict__ W,
                                                   unsigned short* __restrict__ Y,
                                                   void* __restrict__ Rv, int N) {
    constexpr int DOUTA = NT * 64;
    __shared__ unsigned short As[128 * 64];   // 16KB, swizzled 16B chunks
    __shared__ unsigned short Bs[128 * 64];
    const int tid  = threadIdx.x;
    const int lane = tid & 63;
    const int w    = tid >> 6;
    const int wm   = w & 1, wn = w >> 1;
    const int m0   = blockIdx.x * 128;
    const int lm   = lane & 15, quad = lane >> 4;

    // staging: chunk = 8 rows x 128B = 1KB = 64 lanes x 16B (linear LDS dest).
    // lane l -> row srow=l>>3, LDS 16B-slot l&7; source k-chunk = (l&7)^srow.
    const int srow = lane >> 3;
    const int sko  = ((lane & 7) ^ srow) * 8;     // global k offset (shorts)
    const int rsw  = lm & 7;                      // read-side row&7

    for (int nt = 0; nt < NT; ++nt) {
        const int n0 = nt * 128;
        f32x4 acc[4][4];
#pragma unroll
        for (int i = 0; i < 4; ++i)
#pragma unroll
            for (int j = 0; j < 4; ++j) acc[i][j] = (f32x4){0.f, 0.f, 0.f, 0.f};

        for (int k0 = 0; k0 < DK; k0 += 64) {
#pragma unroll
            for (int c = 0; c < 4; ++c) {
                int ch = 4 * w + c;                         // chunk 0..15
                int ra = min(m0 + ch * 8 + srow, N - 1);    // clamp M tail
                gld_lds16(As + ch * 512, A + (size_t)ra * DK + k0 + sko);
                int na = n0 + ch * 8 + srow;                // W rows in bounds
                gld_lds16(Bs + ch * 512, W + (size_t)na * DK + k0 + sko);
            }
            __syncthreads();

#pragma unroll
            for (int kk = 0; kk < 2; ++kk) {
                const int xo = (quad ^ (kk * 4) ^ rsw) * 8; // swizzled 16B slot
                bf16x8 af[4], bfr[4];
#pragma unroll
                for (int mt = 0; mt < 4; ++mt)
                    af[mt] = *reinterpret_cast<const bf16x8*>(
                        As + (wm * 64 + mt * 16 + lm) * 64 + xo);
#pragma unroll
                for (int ntf = 0; ntf < 4; ++ntf)
                    bfr[ntf] = *reinterpret_cast<const bf16x8*>(
                        Bs + (wn * 64 + ntf * 16 + lm) * 64 + xo);
#pragma unroll
                for (int mt = 0; mt < 4; ++mt)
#pragma unroll
                    for (int ntf = 0; ntf < 4; ++ntf)
                        acc[mt][ntf] = __builtin_amdgcn_mfma_f32_16x16x32_bf16(
                            af[mt], bfr[ntf], acc[mt][ntf], 0, 0, 0);
            }
            __syncthreads();
        }

        const bool yPart = (n0 < DOUTA);
#pragma unroll
        for (int mt = 0; mt < 4; ++mt) {
#pragma unroll
            for (int ntf = 0; ntf < 4; ++ntf) {
                int gn = n0 + wn * 64 + ntf * 16 + lm;
#pragma unroll
                for (int reg = 0; reg < 4; ++reg) {
                    int gm = m0 + wm * 64 + mt * 16 + quad * 4 + reg;
                    if (gm < N) {
                        float v = acc[mt][ntf][reg];
                        if (yPart) {
                            Y[(size_t)gm * DOUTA + gn] = f2b(v);
                        } else if (RF32) {
                            ((float*)Rv)[(size_t)gm * DOUTA + (gn - DOUTA)] = v;
                        } else {
                            ((unsigned short*)Rv)[(size_t)gm * DOUTA + (gn - DOUTA)] = f2b(v);
                        }
                    }
                }
            }
        }
    }
}

// ---------------------------------------------------------------------------
// layer-1 aggregate: H = relu(mean(Y[nbrs]) + bias + R), width 256.
// One wave per node; wave halves process two edges (32 lanes x 16B).
// ---------------------------------------------------------------------------
__global__ __launch_bounds__(256) void k_agg256(const unsigned short* __restrict__ Y,
                                                const unsigned short* __restrict__ Rb,
                                                const float* __restrict__ bias,
                                                const float* __restrict__ invdeg,
                                                const int* __restrict__ rowptr,
                                                const int* __restrict__ col,
                                                unsigned short* __restrict__ H, int N) {
    int g = blockIdx.x * 256 + threadIdx.x;
    int node = g >> 6;
    int lane = g & 63;
    if (node >= N) return;
    int half = lane >> 5, sub = lane & 31;
    int beg = rowptr[node], end = rowptr[node + 1];
    const unsigned short* yb = Y + sub * 8;
    float a[8];
#pragma unroll
    for (int j = 0; j < 8; ++j) a[j] = 0.f;
    int e = beg;
    for (; e + 7 < end; e += 8) {                 // 4 pairs = 8 edges in flight
        int s[4];
#pragma unroll
        for (int u = 0; u < 4; ++u) s[u] = col[e + 2 * u + half];
        bf16x8 v[4];
#pragma unroll
        for (int u = 0; u < 4; ++u)
            v[u] = *reinterpret_cast<const bf16x8*>(yb + (size_t)s[u] * 256);
#pragma unroll
        for (int u = 0; u < 4; ++u)
#pragma unroll
            for (int j = 0; j < 8; ++j) a[j] += b2f((unsigned short)v[u][j]);
    }
    for (; e + 1 < end; e += 2) {                 // leftover pairs
        int s0 = col[e + half];
        bf16x8 v0 = *reinterpret_cast<const bf16x8*>(yb + (size_t)s0 * 256);
#pragma unroll
        for (int j = 0; j < 8; ++j) a[j] += b2f((unsigned short)v0[j]);
    }
    if (e < end && half == 0) {                   // odd final edge: half 0 only
        int s0 = col[e];
        bf16x8 v0 = *reinterpret_cast<const bf16x8*>(yb + (size_t)s0 * 256);
#pragma unroll
        for (int j = 0; j < 8; ++j) a[j] += b2f((unsigned short)v0[j]);
    }
#pragma unroll
    for (int j = 0; j < 8; ++j) a[j] += __shfl_xor(a[j], 32);
    if (half == 0) {
        float inv = invdeg[node];
        int c = sub * 8;
        bf16x8 r = *reinterpret_cast<const bf16x8*>(Rb + (size_t)node * 256 + c);
        f32x4 b0 = *reinterpret_cast<const f32x4*>(bias + c);
        f32x4 b1v = *reinterpret_cast<const f32x4*>(bias + c + 4);
        bf16x8 o;
#pragma unroll
        for (int j = 0; j < 8; ++j) {
            float bj = (j < 4) ? b0[j] : b1v[j - 4];
            float ov = fmaxf(a[j] * inv + bj + b2f((unsigned short)r[j]), 0.f);
            o[j] = (short)f2b(ov);
        }
        *reinterpret_cast<bf16x8*>(H + (size_t)node * 256 + c) = o;
    }
}

// ---------------------------------------------------------------------------
// layer-2 aggregate: O = mean(Y[nbrs]) + bias + R, width 128, fp32 out.
// Wave halves process two edges: 32 lanes x 8B per 256B row.
// ---------------------------------------------------------------------------
__global__ __launch_bounds__(256) void k_agg128(const unsigned short* __restrict__ Y,
                                                const float* __restrict__ Rf,
                                                const float* __restrict__ bias,
                                                const float* __restrict__ invdeg,
                                                const int* __restrict__ rowptr,
                                                const int* __restrict__ col,
                                                float* __restrict__ O, int N) {
    int g = blockIdx.x * 256 + threadIdx.x;
    int node = g >> 6;
    int lane = g & 63;
    if (node >= N) return;
    int half = lane >> 5, sub = lane & 31;
    int beg = rowptr[node], end = rowptr[node + 1];
    const unsigned short* yb = Y + sub * 4;
    float a0 = 0, a1 = 0, a2 = 0, a3 = 0;
    int e = beg;
    for (; e + 7 < end; e += 8) {                 // 4 pairs = 8 edges in flight
        int s[4];
#pragma unroll
        for (int u = 0; u < 4; ++u) s[u] = col[e + 2 * u + half];
        ushort4 v[4];
#pragma unroll
        for (int u = 0; u < 4; ++u)
            v[u] = *reinterpret_cast<const ushort4*>(yb + (size_t)s[u] * 128);
#pragma unroll
        for (int u = 0; u < 4; ++u) {
            a0 += b2f(v[u].x); a1 += b2f(v[u].y);
            a2 += b2f(v[u].z); a3 += b2f(v[u].w);
        }
    }
    for (; e + 1 < end; e += 2) {
        int s0 = col[e + half];
        ushort4 v0 = *reinterpret_cast<const ushort4*>(yb + (size_t)s0 * 128);
        a0 += b2f(v0.x); a1 += b2f(v0.y); a2 += b2f(v0.z); a3 += b2f(v0.w);
    }
    if (e < end && half == 0) {
        int s0 = col[e];
        ushort4 v0 = *reinterpret_cast<const ushort4*>(yb + (size_t)s0 * 128);
        a0 += b2f(v0.x); a1 += b2f(v0.y); a2 += b2f(v0.z); a3 += b2f(v0.w);
    }
    a0 += __shfl_xor(a0, 32);
    a1 += __shfl_xor(a1, 32);
    a2 += __shfl_xor(a2, 32);
    a3 += __shfl_xor(a3, 32);
    if (half == 0) {
        float inv = invdeg[node];
        int c = sub * 4;
        f32x4 r = *reinterpret_cast<const f32x4*>(Rf + (size_t)node * 128 + c);
        f32x4 bv = *reinterpret_cast<const f32x4*>(bias + c);
        f32x4 o;
        o[0] = a0 * inv + bv[0] + r[0];
        o[1] = a1 * inv + bv[1] + r[1];
        o[2] = a2 * inv + bv[2] + r[2];
        o[3] = a3 * inv + bv[3] + r[3];
        *reinterpret_cast<f32x4*>(O + (size_t)node * 128 + c) = o;
    }
}

// ---------------------------------------------------------------------------
extern "C" void kernel_launch(void* const* d_in, const int* in_sizes, int n_in,
                              void* d_out, int out_size, void* d_ws, size_t ws_size,
                              hipStream_t stream) {
    const float* x   = (const float*)d_in[0];
    const int*   ei  = (const int*)d_in[1];
    const float* W1l = (const float*)d_in[2];
    const float* b1  = (const float*)d_in[3];
    const float* W1r = (const float*)d_in[4];
    const float* W2l = (const float*)d_in[5];
    const float* b2  = (const float*)d_in[6];
    const float* W2r = (const float*)d_in[7];
    float* out = (float*)d_out;

    const int N = in_sizes[0] / DK;   // 100000
    const int E = in_sizes[1] / 2;    // 1600000
    const int* src = ei;
    const int* dst = ei + E;

    // workspace regions (each N*256 shorts = 51.2 MB):
    //   xb | y1b (y2b aliases after agg256) | r1b (r2f aliases) | hb
    //   Wb1 Wb2 | invdeg | rowptr | col | bsum | boff
    // CSR temporaries alias dead GEMM buffers:
    //   scratch u32[E] -> hb ; hist/hoff -> y1b
    unsigned short* xb  = (unsigned short*)d_ws;
    unsigned short* y1b = xb + (size_t)N * 256;
    unsigned short* r1b = y1b + (size_t)N * 256;
    unsigned short* hb  = r1b + (size_t)N * 256;
    unsigned short* Wb1 = hb + (size_t)N * 256;
    unsigned short* Wb2 = Wb1 + 512 * 256;
    float* invdeg = (float*)(Wb2 + 256 * 256);
    int* rowptr = (int*)(invdeg + N);
    int* col    = rowptr + (N + 1);
    int* bsum   = col + E;
    int* boff   = bsum + 512;
    unsigned short* y2b = y1b;          // y1b dead after k_agg256
    float* r2f = (float*)r1b;           // r1b dead after k_agg256

    const int NBUK = (N + BN - 1) / BN;       // 391 buckets
    const int NH   = NBUK * NBLK;             // 200192 histogram entries
    unsigned* scratch = (unsigned*)hb;        // dead before k_agg256 writes hb
    int* hist  = (int*)y1b;                   // dead before layer-1 GEMM
    int* hoff  = hist + NH;
    int* tot2  = boff + 512;                  // dummy total sink

    // ---- conversions to bf16 ----
    k_cvt<<<(N * 64 + 255) / 256, 256, 0, stream>>>(x, xb, N * 64);
    k_cvtw<<<192, 256, 0, stream>>>(W1l, W1r, W2l, W2r, Wb1, Wb2);

    // ---- CSR build (counting sort; rowptr/invdeg fused into scatter) ----
    const int NB2 = (NH + 1023) / 1024;       // 196 scan blocks for histogram
    k_hist<<<NBLK, 256, NBUK * sizeof(int), stream>>>(dst, hist, E, NBUK);
    k_scan_a<<<NB2, 256, 0, stream>>>(hist, bsum, NH);
    k_scan_b<<<1, 256, 0, stream>>>(bsum, boff, tot2, NB2);
    k_scan_c2<<<NB2, 256, 0, stream>>>(hist, boff, hoff, NH);
    k_part<<<NBLK, 256, NBUK * sizeof(int), stream>>>(src, dst, hoff, scratch, E, NBUK);
    k_scatter3<<<NBUK, 256, 0, stream>>>(scratch, hoff, rowptr, invdeg, col, E, NBUK, N);

    int mTiles = (N + 127) / 128;       // 782
    int aggBlocks = (N + 3) / 4;        // 4 nodes (waves) per block

    // ---- layer 1 ----
    k_gemm_bf16<false, 4><<<mTiles, 256, 0, stream>>>(xb, Wb1, y1b, r1b, N);
    k_agg256<<<aggBlocks, 256, 0, stream>>>(y1b, r1b, b1, invdeg, rowptr, col, hb, N);

    // ---- layer 2 ----
    k_gemm_bf16<true, 2><<<mTiles, 256, 0, stream>>>(hb, Wb2, y2b, r2f, N);
    k_agg128<<<aggBlocks, 256, 0, stream>>>(y2b, r2f, b2, invdeg, rowptr, col, out, N);
}